// Round 2
// baseline (5186.580 us; speedup 1.0000x reference)
//
#include <hip/hip_runtime.h>
#include <hip/hip_bf16.h>

typedef unsigned short u16;
typedef unsigned int u32;

constexpr int B_ = 8, T_ = 512, C_ = 1024, H_ = 16, E_ = 64, L_ = 2048;

typedef __bf16 bf16x8 __attribute__((ext_vector_type(8)));
typedef float f32x4 __attribute__((ext_vector_type(4)));

__device__ inline float bf2f(u16 h) { return __uint_as_float(((u32)h) << 16); }
__device__ inline u16 f2bf(float f) {
  u32 u = __float_as_uint(f);
  u32 r = (u + 0x7fffu + ((u >> 16) & 1u)) >> 16;
  return (u16)r;
}

// ------- transpose + downcast: in f32 (R x Ccols) -> out bf16 (Ccols x R) ----
__global__ __launch_bounds__(256) void transpose_f32_bf16(const float* __restrict__ in,
                                                          u16* __restrict__ out,
                                                          int R, int Ccols) {
  __shared__ u16 tile[64][65];
  const int r0 = blockIdx.y * 64;
  const int c0 = blockIdx.x * 64;
  const int tr = threadIdx.x >> 6;  // 0..3
  const int tc = threadIdx.x & 63;
#pragma unroll
  for (int i = 0; i < 16; ++i)
    tile[tr + i * 4][tc] = f2bf(in[(size_t)(r0 + tr + i * 4) * Ccols + c0 + tc]);
  __syncthreads();
#pragma unroll
  for (int i = 0; i < 16; ++i)
    out[(size_t)(c0 + tr + i * 4) * R + r0 + tc] = tile[tc][tr + i * 4];
}

// ---------------- GEMM: C[M,N] = A[M,K] @ BT[N,K]^T + bias[n] ----------------
// MODE 0: A = f32, scatter bf16 qkv into (B,H,T,E) head layouts out0/out1/out2
// MODE 1: A = bf16, f32 row-major store to outf
template <int MODE>
__global__ __launch_bounds__(256) void gemm_bt(const void* __restrict__ Araw,
                                               const u16* __restrict__ BT,
                                               const float* __restrict__ bias,
                                               u16* __restrict__ out0,
                                               u16* __restrict__ out1,
                                               u16* __restrict__ out2,
                                               float* __restrict__ outf,
                                               int M, int N, int K) {
  __shared__ __align__(16) u16 As[64 * 40];
  __shared__ __align__(16) u16 Bs[64 * 40];
  const int tid = threadIdx.x;
  const int lane = tid & 63;
  const int wave = tid >> 6;
  const int wm = (wave >> 1) * 32;  // 2x2 wave grid
  const int wn = (wave & 1) * 32;
  const int m0 = blockIdx.y * 64;
  const int n0 = blockIdx.x * 64;

  const int lrow = tid >> 2;        // 0..63
  const int lcol = (tid & 3) * 8;   // 0,8,16,24

  const float* Apf = (const float*)Araw + (size_t)(m0 + lrow) * K + lcol;
  const u16* Aph = (const u16*)Araw + (size_t)(m0 + lrow) * K + lcol;
  const u16* Bp = BT + (size_t)(n0 + lrow) * K + lcol;
  u16* AsW = As + lrow * 40 + lcol;
  u16* BsW = Bs + lrow * 40 + lcol;

  const int fm = lane & 15;         // fragment row/col within 16-tile
  const int fk = (lane >> 4) * 8;   // fragment k base

  f32x4 acc00 = {0.f, 0.f, 0.f, 0.f};
  f32x4 acc01 = {0.f, 0.f, 0.f, 0.f};
  f32x4 acc10 = {0.f, 0.f, 0.f, 0.f};
  f32x4 acc11 = {0.f, 0.f, 0.f, 0.f};

  for (int k0 = 0; k0 < K; k0 += 32) {
    if (MODE == 0) {
      const float4 a0 = *(const float4*)Apf;
      const float4 a1 = *(const float4*)(Apf + 4);
      uint4 packed;
      packed.x = (u32)f2bf(a0.x) | ((u32)f2bf(a0.y) << 16);
      packed.y = (u32)f2bf(a0.z) | ((u32)f2bf(a0.w) << 16);
      packed.z = (u32)f2bf(a1.x) | ((u32)f2bf(a1.y) << 16);
      packed.w = (u32)f2bf(a1.z) | ((u32)f2bf(a1.w) << 16);
      *(uint4*)AsW = packed;
      Apf += 32;
    } else {
      *(uint4*)AsW = *(const uint4*)Aph;
      Aph += 32;
    }
    *(uint4*)BsW = *(const uint4*)Bp;
    Bp += 32;
    __syncthreads();
    bf16x8 af0 = *(const bf16x8*)(As + (wm + fm) * 40 + fk);
    bf16x8 af1 = *(const bf16x8*)(As + (wm + 16 + fm) * 40 + fk);
    bf16x8 bg0 = *(const bf16x8*)(Bs + (wn + fm) * 40 + fk);
    bf16x8 bg1 = *(const bf16x8*)(Bs + (wn + 16 + fm) * 40 + fk);
    acc00 = __builtin_amdgcn_mfma_f32_16x16x32_bf16(af0, bg0, acc00, 0, 0, 0);
    acc01 = __builtin_amdgcn_mfma_f32_16x16x32_bf16(af0, bg1, acc01, 0, 0, 0);
    acc10 = __builtin_amdgcn_mfma_f32_16x16x32_bf16(af1, bg0, acc10, 0, 0, 0);
    acc11 = __builtin_amdgcn_mfma_f32_16x16x32_bf16(af1, bg1, acc11, 0, 0, 0);
    __syncthreads();
  }

  const int rbase = (lane >> 4) * 4;
  const int cbase = lane & 15;
  f32x4 accs[2][2] = {{acc00, acc01}, {acc10, acc11}};
#pragma unroll
  for (int i = 0; i < 2; ++i)
#pragma unroll
    for (int j = 0; j < 2; ++j) {
      const int n = n0 + wn + j * 16 + cbase;
      const float bv = bias[n];
#pragma unroll
      for (int r = 0; r < 4; ++r) {
        const int m = m0 + wm + i * 16 + rbase + r;
        const float v = accs[i][j][r] + bv;
        if (MODE == 0) {
          const int seg = n >> 10;         // 0:q 1:k 2:v
          const int c = n & 1023;
          u16* dst = (seg == 0) ? out0 : ((seg == 1) ? out1 : out2);
          // (b,h,t,e) = (m>>9, c>>6, m&511, c&63)
          const int idx = ((((m >> 9) * H_ + (c >> 6)) * T_) + (m & 511)) * E_ + (c & 63);
          dst[idx] = f2bf(v);
        } else {
          outf[(size_t)m * N + n] = v;
        }
      }
    }
}

// ---------------- attention: one wave per (b,h,t) query row ------------------
// cache K/V are f32; new K/V (from qkv GEMM) are bf16 in workspace
__global__ __launch_bounds__(256) void attn_kernel(const u16* __restrict__ qh,
                                                   const float* __restrict__ kc,
                                                   const float* __restrict__ vc,
                                                   const u16* __restrict__ kn,
                                                   const u16* __restrict__ vn,
                                                   u16* __restrict__ y2) {
  const int w = threadIdx.x >> 6;
  const int lane = threadIdx.x & 63;
  const int wid = blockIdx.x * 4 + w;
  const int t = wid & (T_ - 1);
  const int bh = wid >> 9;           // T_ = 512
  const int h = bh & (H_ - 1);
  const int b = bh >> 4;

  __shared__ float qs[4][64];

  const u16* qrow = qh + ((size_t)bh * T_ + t) * E_;
  qs[w][lane] = bf2f(qrow[lane]) * 0.125f;  // fold 1/sqrt(E)
  __syncthreads();

  const float* Kc = kc + (size_t)bh * L_ * E_;
  const float* Vc = vc + (size_t)bh * L_ * E_;
  const u16* Kn = kn + (size_t)bh * T_ * E_;
  const u16* Vn = vn + (size_t)bh * T_ * E_;

  const int smax = L_ + t;                 // inclusive causal bound
  const int nchunk = (smax + 64) >> 6;

  float m_run = -1e30f, l_run = 0.f, yacc = 0.f;

  for (int c0 = 0; c0 < nchunk; ++c0) {
    const int sbase = c0 << 6;
    const bool incache = sbase < L_;       // L_ % 64 == 0: chunk never straddles

    // phase 1: lane <-> key position
    float sc = 0.f;
    const float* qp = qs[w];
    if (incache) {
      const float4* krow = (const float4*)(Kc + (size_t)(sbase + lane) * E_);
#pragma unroll
      for (int jj = 0; jj < 16; ++jj) {
        const float4 kv = krow[jj];
        sc = fmaf(qp[jj * 4 + 0], kv.x, sc);
        sc = fmaf(qp[jj * 4 + 1], kv.y, sc);
        sc = fmaf(qp[jj * 4 + 2], kv.z, sc);
        sc = fmaf(qp[jj * 4 + 3], kv.w, sc);
      }
    } else {
      const uint4* krow = (const uint4*)(Kn + (size_t)(sbase - L_ + lane) * E_);
#pragma unroll
      for (int jj = 0; jj < 8; ++jj) {
        const uint4 kv = krow[jj];
        sc = fmaf(qp[jj * 8 + 0], __uint_as_float(kv.x << 16), sc);
        sc = fmaf(qp[jj * 8 + 1], __uint_as_float(kv.x & 0xffff0000u), sc);
        sc = fmaf(qp[jj * 8 + 2], __uint_as_float(kv.y << 16), sc);
        sc = fmaf(qp[jj * 8 + 3], __uint_as_float(kv.y & 0xffff0000u), sc);
        sc = fmaf(qp[jj * 8 + 4], __uint_as_float(kv.z << 16), sc);
        sc = fmaf(qp[jj * 8 + 5], __uint_as_float(kv.z & 0xffff0000u), sc);
        sc = fmaf(qp[jj * 8 + 6], __uint_as_float(kv.w << 16), sc);
        sc = fmaf(qp[jj * 8 + 7], __uint_as_float(kv.w & 0xffff0000u), sc);
      }
    }
    const int s = sbase + lane;
    const bool valid = (s <= smax);
    sc = valid ? sc : -1e30f;

    float cmax = sc;
#pragma unroll
    for (int off = 32; off; off >>= 1) cmax = fmaxf(cmax, __shfl_xor(cmax, off, 64));
    const float m_new = fmaxf(m_run, cmax);
    const float alpha = __expf(m_run - m_new);
    const float p = valid ? __expf(sc - m_new) : 0.f;
    float psum = p;
#pragma unroll
    for (int off = 32; off; off >>= 1) psum += __shfl_xor(psum, off, 64);
    l_run = l_run * alpha + psum;
    m_run = m_new;

    // phase 2: lane <-> head dim e
    float add = 0.f;
    if (incache) {
      const float* Vp = Vc + (size_t)sbase * E_;
#pragma unroll 8
      for (int i = 0; i < 64; ++i) {
        const float pi = __shfl(p, i, 64);
        add = fmaf(pi, Vp[i * 64 + lane], add);
      }
    } else {
      const u16* Vp = Vn + (size_t)(sbase - L_) * E_;
#pragma unroll 8
      for (int i = 0; i < 64; ++i) {
        const float pi = __shfl(p, i, 64);
        add = fmaf(pi, bf2f(Vp[i * 64 + lane]), add);
      }
    }
    yacc = yacc * alpha + add;
  }

  y2[(size_t)(b * T_ + t) * C_ + h * E_ + lane] = f2bf(yacc / l_run);
}

// ---------------- launch -----------------------------------------------------
extern "C" void kernel_launch(void* const* d_in, const int* in_sizes, int n_in,
                              void* d_out, int out_size, void* d_ws, size_t ws_size,
                              hipStream_t stream) {
  const float* x = (const float*)d_in[0];
  const float* kc = (const float*)d_in[1];
  const float* vc = (const float*)d_in[2];
  const float* Wqkv = (const float*)d_in[3];
  const float* bqkv = (const float*)d_in[4];
  const float* Wproj = (const float*)d_in[5];
  const float* bproj = (const float*)d_in[6];
  float* out = (float*)d_out;

  u16* qh = (u16*)d_ws;                 // B*H*T*E = 4194304 bf16
  u16* kh = qh + 4194304;
  u16* vh = kh + 4194304;
  u16* y2 = vh + 4194304;               // B*T*C  = 4194304 bf16
  u16* WqT = y2 + 4194304;              // 3072x1024 bf16
  u16* WpT = WqT + 3145728;             // 1024x1024 bf16

  transpose_f32_bf16<<<dim3(48, 16), 256, 0, stream>>>(Wqkv, WqT, 1024, 3072);
  transpose_f32_bf16<<<dim3(16, 16), 256, 0, stream>>>(Wproj, WpT, 1024, 1024);

  // qkv = x @ Wqkv + bqkv, scattered to head layout (bf16)
  gemm_bt<0><<<dim3(48, 64), 256, 0, stream>>>(x, WqT, bqkv, qh, kh, vh, nullptr,
                                               4096, 3072, 1024);

  attn_kernel<<<dim3(B_ * H_ * T_ / 4), 256, 0, stream>>>(qh, kc, vc, kh, vh, y2);

  // out = y @ Wproj + bproj (f32 out)
  gemm_bt<1><<<dim3(16, 64), 256, 0, stream>>>(y2, WpT, bproj, nullptr, nullptr,
                                               nullptr, out, 4096, 1024, 1024);
}

// Round 3
// 455.923 us; speedup vs baseline: 11.3760x; 11.3760x over previous
//
#include <hip/hip_runtime.h>
#include <hip/hip_bf16.h>

typedef unsigned short u16;
typedef unsigned int u32;

constexpr int B_ = 8, T_ = 512, C_ = 1024, H_ = 16, E_ = 64, L_ = 2048;

typedef __bf16 bf16x8 __attribute__((ext_vector_type(8)));
typedef float f32x4 __attribute__((ext_vector_type(4)));

__device__ inline float bf2f(u16 h) { return __uint_as_float(((u32)h) << 16); }
__device__ inline u16 f2bf(float f) {
  u32 u = __float_as_uint(f);
  u32 r = (u + 0x7fffu + ((u >> 16) & 1u)) >> 16;
  return (u16)r;
}

// ------- transpose + downcast: in f32 (R x Ccols) -> out bf16 (Ccols x R) ----
__global__ __launch_bounds__(256) void transpose_f32_bf16(const float* __restrict__ in,
                                                          u16* __restrict__ out,
                                                          int R, int Ccols) {
  __shared__ u16 tile[64][65];
  const int r0 = blockIdx.y * 64;
  const int c0 = blockIdx.x * 64;
  const int tr = threadIdx.x >> 6;  // 0..3
  const int tc = threadIdx.x & 63;
#pragma unroll
  for (int i = 0; i < 16; ++i)
    tile[tr + i * 4][tc] = f2bf(in[(size_t)(r0 + tr + i * 4) * Ccols + c0 + tc]);
  __syncthreads();
#pragma unroll
  for (int i = 0; i < 16; ++i)
    out[(size_t)(c0 + tr + i * 4) * R + r0 + tc] = tile[tc][tr + i * 4];
}

// ---------------- GEMM: C[M,N] = A[M,K] @ BT[N,K]^T + bias[n] ----------------
// MODE 0: A = f32, scatter bf16 qkv into (B,H,T,E) head layouts out0/out1/out2
// MODE 1: A = bf16, f32 row-major store to outf
template <int MODE>
__global__ __launch_bounds__(256) void gemm_bt(const void* __restrict__ Araw,
                                               const u16* __restrict__ BT,
                                               const float* __restrict__ bias,
                                               u16* __restrict__ out0,
                                               u16* __restrict__ out1,
                                               u16* __restrict__ out2,
                                               float* __restrict__ outf,
                                               int M, int N, int K) {
  __shared__ __align__(16) u16 As[64 * 40];
  __shared__ __align__(16) u16 Bs[64 * 40];
  const int tid = threadIdx.x;
  const int lane = tid & 63;
  const int wave = tid >> 6;
  const int wm = (wave >> 1) * 32;  // 2x2 wave grid
  const int wn = (wave & 1) * 32;
  const int m0 = blockIdx.y * 64;
  const int n0 = blockIdx.x * 64;

  const int lrow = tid >> 2;        // 0..63
  const int lcol = (tid & 3) * 8;   // 0,8,16,24

  const float* Apf = (const float*)Araw + (size_t)(m0 + lrow) * K + lcol;
  const u16* Aph = (const u16*)Araw + (size_t)(m0 + lrow) * K + lcol;
  const u16* Bp = BT + (size_t)(n0 + lrow) * K + lcol;
  u16* AsW = As + lrow * 40 + lcol;
  u16* BsW = Bs + lrow * 40 + lcol;

  const int fm = lane & 15;         // fragment row/col within 16-tile
  const int fk = (lane >> 4) * 8;   // fragment k base

  f32x4 acc00 = {0.f, 0.f, 0.f, 0.f};
  f32x4 acc01 = {0.f, 0.f, 0.f, 0.f};
  f32x4 acc10 = {0.f, 0.f, 0.f, 0.f};
  f32x4 acc11 = {0.f, 0.f, 0.f, 0.f};

  for (int k0 = 0; k0 < K; k0 += 32) {
    if (MODE == 0) {
      const float4 a0 = *(const float4*)Apf;
      const float4 a1 = *(const float4*)(Apf + 4);
      uint4 packed;
      packed.x = (u32)f2bf(a0.x) | ((u32)f2bf(a0.y) << 16);
      packed.y = (u32)f2bf(a0.z) | ((u32)f2bf(a0.w) << 16);
      packed.z = (u32)f2bf(a1.x) | ((u32)f2bf(a1.y) << 16);
      packed.w = (u32)f2bf(a1.z) | ((u32)f2bf(a1.w) << 16);
      *(uint4*)AsW = packed;
      Apf += 32;
    } else {
      *(uint4*)AsW = *(const uint4*)Aph;
      Aph += 32;
    }
    *(uint4*)BsW = *(const uint4*)Bp;
    Bp += 32;
    __syncthreads();
    bf16x8 af0 = *(const bf16x8*)(As + (wm + fm) * 40 + fk);
    bf16x8 af1 = *(const bf16x8*)(As + (wm + 16 + fm) * 40 + fk);
    bf16x8 bg0 = *(const bf16x8*)(Bs + (wn + fm) * 40 + fk);
    bf16x8 bg1 = *(const bf16x8*)(Bs + (wn + 16 + fm) * 40 + fk);
    acc00 = __builtin_amdgcn_mfma_f32_16x16x32_bf16(af0, bg0, acc00, 0, 0, 0);
    acc01 = __builtin_amdgcn_mfma_f32_16x16x32_bf16(af0, bg1, acc01, 0, 0, 0);
    acc10 = __builtin_amdgcn_mfma_f32_16x16x32_bf16(af1, bg0, acc10, 0, 0, 0);
    acc11 = __builtin_amdgcn_mfma_f32_16x16x32_bf16(af1, bg1, acc11, 0, 0, 0);
    __syncthreads();
  }

  const int rbase = (lane >> 4) * 4;
  const int cbase = lane & 15;
  f32x4 accs[2][2] = {{acc00, acc01}, {acc10, acc11}};
#pragma unroll
  for (int i = 0; i < 2; ++i)
#pragma unroll
    for (int j = 0; j < 2; ++j) {
      const int n = n0 + wn + j * 16 + cbase;
      const float bv = bias[n];
#pragma unroll
      for (int r = 0; r < 4; ++r) {
        const int m = m0 + wm + i * 16 + rbase + r;
        const float v = accs[i][j][r] + bv;
        if (MODE == 0) {
          const int seg = n >> 10;         // 0:q 1:k 2:v
          const int c = n & 1023;
          u16* dst = (seg == 0) ? out0 : ((seg == 1) ? out1 : out2);
          // (b,h,t,e) = (m>>9, c>>6, m&511, c&63)
          const int idx = ((((m >> 9) * H_ + (c >> 6)) * T_) + (m & 511)) * E_ + (c & 63);
          dst[idx] = f2bf(v);
        } else {
          outf[(size_t)m * N + n] = v;
        }
      }
    }
}

// -------- MFMA flash attention: block = (b,h, 64-q tile), 4 waves x 16 q -----
// K/V cache f32, new K/V bf16 (head layout). Stages 64-key chunks into LDS as
// bf16: Ks[key][e] (stride 72), Vts[e][key] (stride 72). Per wave: S = Q.K^T
// (8 MFMAs), online softmax (row = (lane>>4)*4+r, col = lane&15), P via
// wave-private LDS re-layout C->A, Y += P.V (8 MFMAs).
__global__ __launch_bounds__(256) void attn_mfma(const u16* __restrict__ qh,
                                                 const float* __restrict__ kc,
                                                 const float* __restrict__ vc,
                                                 const u16* __restrict__ kn,
                                                 const u16* __restrict__ vn,
                                                 u16* __restrict__ y2) {
  __shared__ __align__(16) u16 Ks[64 * 72];
  __shared__ __align__(16) u16 Vts[64 * 72];
  __shared__ __align__(16) u16 Ps[4][16 * 72];

  const int tid = threadIdx.x;
  const int lane = tid & 63;
  const int w = tid >> 6;
  const int bh = blockIdx.x >> 3;
  const int qt = blockIdx.x & 7;
  const int h = bh & (H_ - 1);
  const int b = bh >> 4;
  const int t0 = qt * 64;

  const int col = lane & 15;            // fragment col / A-row
  const int fk = (lane >> 4) * 8;       // fragment k base
  const int rbase = (lane >> 4) * 4;    // D-layout row base

  // Q fragments (A-layout), resident for whole kernel
  const u16* qbase = qh + ((size_t)bh * T_ + t0 + w * 16 + col) * E_;
  const bf16x8 qf0 = *(const bf16x8*)(qbase + fk);
  const bf16x8 qf1 = *(const bf16x8*)(qbase + 32 + fk);

  // staging role: row = key index, ecol0 = 16-wide e quarter
  const int srow = tid >> 2;
  const int ecol0 = (tid & 3) * 16;

  f32x4 Y[4] = {{0.f, 0.f, 0.f, 0.f}, {0.f, 0.f, 0.f, 0.f},
                {0.f, 0.f, 0.f, 0.f}, {0.f, 0.f, 0.f, 0.f}};
  float m_run[4] = {-1e30f, -1e30f, -1e30f, -1e30f};
  float l_run[4] = {0.f, 0.f, 0.f, 0.f};

  const int qmin_w = L_ + t0 + w * 16;          // smallest causal bound in wave
  const int nchunk = (L_ + t0 + 64) >> 6;

  for (int c0 = 0; c0 < nchunk; ++c0) {
    const int sbase = c0 << 6;
    __syncthreads();
    // ---- stage K chunk -> Ks[key][e], V chunk -> Vts[e][key] (bf16)
    if (sbase < L_) {
      const float* kp = kc + ((size_t)bh * L_ + sbase + srow) * E_ + ecol0;
      const float* vp = vc + ((size_t)bh * L_ + sbase + srow) * E_ + ecol0;
      float kv[16], vv[16];
      *(float4*)(kv + 0) = *(const float4*)(kp + 0);
      *(float4*)(kv + 4) = *(const float4*)(kp + 4);
      *(float4*)(kv + 8) = *(const float4*)(kp + 8);
      *(float4*)(kv + 12) = *(const float4*)(kp + 12);
      *(float4*)(vv + 0) = *(const float4*)(vp + 0);
      *(float4*)(vv + 4) = *(const float4*)(vp + 4);
      *(float4*)(vv + 8) = *(const float4*)(vp + 8);
      *(float4*)(vv + 12) = *(const float4*)(vp + 12);
      uint4 p0, p1;
      p0.x = (u32)f2bf(kv[0]) | ((u32)f2bf(kv[1]) << 16);
      p0.y = (u32)f2bf(kv[2]) | ((u32)f2bf(kv[3]) << 16);
      p0.z = (u32)f2bf(kv[4]) | ((u32)f2bf(kv[5]) << 16);
      p0.w = (u32)f2bf(kv[6]) | ((u32)f2bf(kv[7]) << 16);
      p1.x = (u32)f2bf(kv[8]) | ((u32)f2bf(kv[9]) << 16);
      p1.y = (u32)f2bf(kv[10]) | ((u32)f2bf(kv[11]) << 16);
      p1.z = (u32)f2bf(kv[12]) | ((u32)f2bf(kv[13]) << 16);
      p1.w = (u32)f2bf(kv[14]) | ((u32)f2bf(kv[15]) << 16);
      *(uint4*)(Ks + srow * 72 + ecol0) = p0;
      *(uint4*)(Ks + srow * 72 + ecol0 + 8) = p1;
#pragma unroll
      for (int j = 0; j < 16; ++j)
        Vts[(ecol0 + j) * 72 + srow] = f2bf(vv[j]);
    } else {
      const u16* kp = kn + ((size_t)bh * T_ + (sbase - L_) + srow) * E_ + ecol0;
      const u16* vp = vn + ((size_t)bh * T_ + (sbase - L_) + srow) * E_ + ecol0;
      *(uint4*)(Ks + srow * 72 + ecol0) = *(const uint4*)kp;
      *(uint4*)(Ks + srow * 72 + ecol0 + 8) = *(const uint4*)(kp + 8);
      u16 vv[16];
      *(uint4*)(vv + 0) = *(const uint4*)vp;
      *(uint4*)(vv + 8) = *(const uint4*)(vp + 8);
#pragma unroll
      for (int j = 0; j < 16; ++j)
        Vts[(ecol0 + j) * 72 + srow] = vv[j];
    }
    __syncthreads();

    // ---- S = Q.K^T for 4 key tiles (D: row=q=(lane>>4)*4+r, col=key=lane&15)
    f32x4 s[4];
#pragma unroll
    for (int t = 0; t < 4; ++t) {
      const bf16x8 kb0 = *(const bf16x8*)(Ks + (t * 16 + col) * 72 + fk);
      const bf16x8 kb1 = *(const bf16x8*)(Ks + (t * 16 + col) * 72 + 32 + fk);
      f32x4 z = {0.f, 0.f, 0.f, 0.f};
      z = __builtin_amdgcn_mfma_f32_16x16x32_bf16(qf0, kb0, z, 0, 0, 0);
      z = __builtin_amdgcn_mfma_f32_16x16x32_bf16(qf1, kb1, z, 0, 0, 0);
#pragma unroll
      for (int r = 0; r < 4; ++r) s[t][r] = z[r] * 0.125f;
    }

    // ---- causal mask (only straddling chunks)
    if (sbase + 63 > qmin_w) {
#pragma unroll
      for (int t = 0; t < 4; ++t) {
        const int keypos = sbase + t * 16 + col;
#pragma unroll
        for (int r = 0; r < 4; ++r)
          if (keypos > qmin_w + rbase + r) s[t][r] = -1e30f;
      }
    }

    // ---- online softmax update
    float alpha[4], rl[4];
#pragma unroll
    for (int r = 0; r < 4; ++r) {
      float mp = fmaxf(fmaxf(s[0][r], s[1][r]), fmaxf(s[2][r], s[3][r]));
      mp = fmaxf(mp, __shfl_xor(mp, 1, 64));
      mp = fmaxf(mp, __shfl_xor(mp, 2, 64));
      mp = fmaxf(mp, __shfl_xor(mp, 4, 64));
      mp = fmaxf(mp, __shfl_xor(mp, 8, 64));
      const float m_new = fmaxf(m_run[r], mp);
      alpha[r] = __expf(m_run[r] - m_new);
      m_run[r] = m_new;
      float ps = 0.f;
#pragma unroll
      for (int t = 0; t < 4; ++t) {
        s[t][r] = __expf(s[t][r] - m_new);
        ps += s[t][r];
      }
      ps += __shfl_xor(ps, 1, 64);
      ps += __shfl_xor(ps, 2, 64);
      ps += __shfl_xor(ps, 4, 64);
      ps += __shfl_xor(ps, 8, 64);
      rl[r] = ps;
      l_run[r] = l_run[r] * alpha[r] + ps;
    }

    // ---- write P (bf16) to wave-private LDS: Ps[q][key], q=rbase+r, key=t*16+col
    u16* psw = Ps[w];
#pragma unroll
    for (int t = 0; t < 4; ++t)
#pragma unroll
      for (int r = 0; r < 4; ++r)
        psw[(rbase + r) * 72 + t * 16 + col] = f2bf(s[t][r]);

    // ---- rescale Y, then Y += P.V
#pragma unroll
    for (int et = 0; et < 4; ++et)
#pragma unroll
      for (int r = 0; r < 4; ++r) Y[et][r] *= alpha[r];

    const bf16x8 pa0 = *(const bf16x8*)(psw + col * 72 + fk);
    const bf16x8 pa1 = *(const bf16x8*)(psw + col * 72 + 32 + fk);
#pragma unroll
    for (int et = 0; et < 4; ++et) {
      const bf16x8 vb0 = *(const bf16x8*)(Vts + (et * 16 + col) * 72 + fk);
      const bf16x8 vb1 = *(const bf16x8*)(Vts + (et * 16 + col) * 72 + 32 + fk);
      Y[et] = __builtin_amdgcn_mfma_f32_16x16x32_bf16(pa0, vb0, Y[et], 0, 0, 0);
      Y[et] = __builtin_amdgcn_mfma_f32_16x16x32_bf16(pa1, vb1, Y[et], 0, 0, 0);
    }
  }

  // ---- epilogue: y2[b,t, h*E + e] = Y / l
  float rcp_l[4];
#pragma unroll
  for (int r = 0; r < 4; ++r) rcp_l[r] = 1.f / l_run[r];
#pragma unroll
  for (int et = 0; et < 4; ++et)
#pragma unroll
    for (int r = 0; r < 4; ++r) {
      const int t_out = t0 + w * 16 + rbase + r;
      y2[((size_t)b * T_ + t_out) * C_ + h * E_ + et * 16 + col] =
          f2bf(Y[et][r] * rcp_l[r]);
    }
}

// ---------------- launch -----------------------------------------------------
extern "C" void kernel_launch(void* const* d_in, const int* in_sizes, int n_in,
                              void* d_out, int out_size, void* d_ws, size_t ws_size,
                              hipStream_t stream) {
  const float* x = (const float*)d_in[0];
  const float* kc = (const float*)d_in[1];
  const float* vc = (const float*)d_in[2];
  const float* Wqkv = (const float*)d_in[3];
  const float* bqkv = (const float*)d_in[4];
  const float* Wproj = (const float*)d_in[5];
  const float* bproj = (const float*)d_in[6];
  float* out = (float*)d_out;

  u16* qh = (u16*)d_ws;                 // B*H*T*E = 4194304 bf16
  u16* kh = qh + 4194304;
  u16* vh = kh + 4194304;
  u16* y2 = vh + 4194304;               // B*T*C  = 4194304 bf16
  u16* WqT = y2 + 4194304;              // 3072x1024 bf16
  u16* WpT = WqT + 3145728;             // 1024x1024 bf16

  transpose_f32_bf16<<<dim3(48, 16), 256, 0, stream>>>(Wqkv, WqT, 1024, 3072);
  transpose_f32_bf16<<<dim3(16, 16), 256, 0, stream>>>(Wproj, WpT, 1024, 1024);

  // qkv = x @ Wqkv + bqkv, scattered to head layout (bf16)
  gemm_bt<0><<<dim3(48, 64), 256, 0, stream>>>(x, WqT, bqkv, qh, kh, vh, nullptr,
                                               4096, 3072, 1024);

  attn_mfma<<<dim3(B_ * H_ * T_ / 64), 256, 0, stream>>>(qh, kc, vc, kh, vh, y2);

  // out = y @ Wproj + bproj (f32 out)
  gemm_bt<1><<<dim3(16, 64), 256, 0, stream>>>(y2, WpT, bproj, nullptr, nullptr,
                                               nullptr, out, 4096, 1024, 1024);
}

// Round 4
// 420.593 us; speedup vs baseline: 12.3316x; 1.0840x over previous
//
#include <hip/hip_runtime.h>
#include <hip/hip_bf16.h>

typedef unsigned short u16;
typedef unsigned int u32;

constexpr int B_ = 8, T_ = 512, C_ = 1024, H_ = 16, E_ = 64, L_ = 2048;
constexpr int S_ = L_ + T_;  // 2560 merged KV length

typedef __bf16 bf16x8 __attribute__((ext_vector_type(8)));
typedef float f32x4 __attribute__((ext_vector_type(4)));

__device__ inline float bf2f(u16 h) { return __uint_as_float(((u32)h) << 16); }
__device__ inline u16 f2bf(float f) {
  u32 u = __float_as_uint(f);
  u32 r = (u + 0x7fffu + ((u >> 16) & 1u)) >> 16;
  return (u16)r;
}

// ---------------- x (f32) -> bf16, 8 elements/thread -------------------------
__global__ __launch_bounds__(256) void convert_f32_bf16(const float* __restrict__ in,
                                                        u16* __restrict__ out) {
  const int i = blockIdx.x * 256 + threadIdx.x;
  const float4 a0 = ((const float4*)in)[i * 2];
  const float4 a1 = ((const float4*)in)[i * 2 + 1];
  uint4 p;
  p.x = (u32)f2bf(a0.x) | ((u32)f2bf(a0.y) << 16);
  p.y = (u32)f2bf(a0.z) | ((u32)f2bf(a0.w) << 16);
  p.z = (u32)f2bf(a1.x) | ((u32)f2bf(a1.y) << 16);
  p.w = (u32)f2bf(a1.z) | ((u32)f2bf(a1.w) << 16);
  ((uint4*)out)[i] = p;
}

// ------- transpose + downcast: in f32 (R x Ccols) -> out bf16 (Ccols x R) ----
__global__ __launch_bounds__(256) void transpose_f32_bf16(const float* __restrict__ in,
                                                          u16* __restrict__ out,
                                                          int R, int Ccols) {
  __shared__ u16 tile[64][65];
  const int r0 = blockIdx.y * 64;
  const int c0 = blockIdx.x * 64;
  const int tr = threadIdx.x >> 6;  // 0..3
  const int tc = threadIdx.x & 63;
#pragma unroll
  for (int i = 0; i < 16; ++i)
    tile[tr + i * 4][tc] = f2bf(in[(size_t)(r0 + tr + i * 4) * Ccols + c0 + tc]);
  __syncthreads();
#pragma unroll
  for (int i = 0; i < 16; ++i)
    out[(size_t)(c0 + tr + i * 4) * R + r0 + tc] = tile[tc][tr + i * 4];
}

// ---- prep: f32 KV cache -> merged bf16 Km[b,h,s,e] and Vtm[b,h,e,s] (s<L) ---
__global__ __launch_bounds__(256) void prep_kv(const float* __restrict__ kc,
                                               const float* __restrict__ vc,
                                               u16* __restrict__ Km,
                                               u16* __restrict__ Vtm) {
  __shared__ u16 vt[64 * 72];
  const int s0 = (blockIdx.x & 31) * 64;
  const int bh = blockIdx.x >> 5;
  const int tid = threadIdx.x;
  const int srow = tid >> 2;
  const int eq = (tid & 3) * 16;

  // K: straight convert
  {
    const float* kp = kc + ((size_t)bh * L_ + s0 + srow) * E_ + eq;
    float kv[16];
    *(float4*)(kv + 0) = *(const float4*)(kp + 0);
    *(float4*)(kv + 4) = *(const float4*)(kp + 4);
    *(float4*)(kv + 8) = *(const float4*)(kp + 8);
    *(float4*)(kv + 12) = *(const float4*)(kp + 12);
    uint4 p0, p1;
    p0.x = (u32)f2bf(kv[0]) | ((u32)f2bf(kv[1]) << 16);
    p0.y = (u32)f2bf(kv[2]) | ((u32)f2bf(kv[3]) << 16);
    p0.z = (u32)f2bf(kv[4]) | ((u32)f2bf(kv[5]) << 16);
    p0.w = (u32)f2bf(kv[6]) | ((u32)f2bf(kv[7]) << 16);
    p1.x = (u32)f2bf(kv[8]) | ((u32)f2bf(kv[9]) << 16);
    p1.y = (u32)f2bf(kv[10]) | ((u32)f2bf(kv[11]) << 16);
    p1.z = (u32)f2bf(kv[12]) | ((u32)f2bf(kv[13]) << 16);
    p1.w = (u32)f2bf(kv[14]) | ((u32)f2bf(kv[15]) << 16);
    u16* kd = Km + ((size_t)bh * S_ + s0 + srow) * E_ + eq;
    *(uint4*)kd = p0;
    *(uint4*)(kd + 8) = p1;
  }
  // V: convert into LDS tile[s][e], then write transposed
  {
    const float* vp = vc + ((size_t)bh * L_ + s0 + srow) * E_ + eq;
    float vv[16];
    *(float4*)(vv + 0) = *(const float4*)(vp + 0);
    *(float4*)(vv + 4) = *(const float4*)(vp + 4);
    *(float4*)(vv + 8) = *(const float4*)(vp + 8);
    *(float4*)(vv + 12) = *(const float4*)(vp + 12);
    uint4 p0, p1;
    p0.x = (u32)f2bf(vv[0]) | ((u32)f2bf(vv[1]) << 16);
    p0.y = (u32)f2bf(vv[2]) | ((u32)f2bf(vv[3]) << 16);
    p0.z = (u32)f2bf(vv[4]) | ((u32)f2bf(vv[5]) << 16);
    p0.w = (u32)f2bf(vv[6]) | ((u32)f2bf(vv[7]) << 16);
    p1.x = (u32)f2bf(vv[8]) | ((u32)f2bf(vv[9]) << 16);
    p1.y = (u32)f2bf(vv[10]) | ((u32)f2bf(vv[11]) << 16);
    p1.z = (u32)f2bf(vv[12]) | ((u32)f2bf(vv[13]) << 16);
    p1.w = (u32)f2bf(vv[14]) | ((u32)f2bf(vv[15]) << 16);
    *(uint4*)(vt + srow * 72 + eq) = p0;
    *(uint4*)(vt + srow * 72 + eq + 8) = p1;
  }
  __syncthreads();
  {
    const int erow = tid >> 2;
    const int sq = (tid & 3) * 16;
    u16 o[16];
#pragma unroll
    for (int j = 0; j < 16; ++j) o[j] = vt[(sq + j) * 72 + erow];
    u16* vd = Vtm + ((size_t)bh * E_ + erow) * S_ + s0 + sq;
    *(uint4*)vd = *(uint4*)(o + 0);
    *(uint4*)(vd + 8) = *(uint4*)(o + 8);
  }
}

// ---------------- GEMM: C[M,N] = A[M,K] @ BT[N,K]^T + bias[n] ----------------
// A bf16 both modes.
// MODE 0: scatter qkv: q (x0.125) -> qh[b,h,t,e]; k -> Km[b,h,L+t,e]; v -> Vtm[b,h,e,L+t]
// MODE 1: f32 row-major store to outf
template <int MODE>
__global__ __launch_bounds__(256) void gemm_bt(const u16* __restrict__ A,
                                               const u16* __restrict__ BT,
                                               const float* __restrict__ bias,
                                               u16* __restrict__ qh,
                                               u16* __restrict__ Km,
                                               u16* __restrict__ Vtm,
                                               float* __restrict__ outf,
                                               int M, int N, int K) {
  __shared__ __align__(16) u16 As[64 * 40];
  __shared__ __align__(16) u16 Bs[64 * 40];
  const int tid = threadIdx.x;
  const int lane = tid & 63;
  const int wave = tid >> 6;
  const int wm = (wave >> 1) * 32;  // 2x2 wave grid
  const int wn = (wave & 1) * 32;
  const int m0 = blockIdx.y * 64;
  const int n0 = blockIdx.x * 64;

  const int lrow = tid >> 2;        // 0..63
  const int lcol = (tid & 3) * 8;   // 0,8,16,24

  const u16* Ap = A + (size_t)(m0 + lrow) * K + lcol;
  const u16* Bp = BT + (size_t)(n0 + lrow) * K + lcol;
  u16* AsW = As + lrow * 40 + lcol;
  u16* BsW = Bs + lrow * 40 + lcol;

  const int fm = lane & 15;         // fragment row/col within 16-tile
  const int fk = (lane >> 4) * 8;   // fragment k base

  f32x4 acc00 = {0.f, 0.f, 0.f, 0.f};
  f32x4 acc01 = {0.f, 0.f, 0.f, 0.f};
  f32x4 acc10 = {0.f, 0.f, 0.f, 0.f};
  f32x4 acc11 = {0.f, 0.f, 0.f, 0.f};

  for (int k0 = 0; k0 < K; k0 += 32) {
    *(uint4*)AsW = *(const uint4*)Ap;
    *(uint4*)BsW = *(const uint4*)Bp;
    Ap += 32;
    Bp += 32;
    __syncthreads();
    bf16x8 af0 = *(const bf16x8*)(As + (wm + fm) * 40 + fk);
    bf16x8 af1 = *(const bf16x8*)(As + (wm + 16 + fm) * 40 + fk);
    bf16x8 bg0 = *(const bf16x8*)(Bs + (wn + fm) * 40 + fk);
    bf16x8 bg1 = *(const bf16x8*)(Bs + (wn + 16 + fm) * 40 + fk);
    acc00 = __builtin_amdgcn_mfma_f32_16x16x32_bf16(af0, bg0, acc00, 0, 0, 0);
    acc01 = __builtin_amdgcn_mfma_f32_16x16x32_bf16(af0, bg1, acc01, 0, 0, 0);
    acc10 = __builtin_amdgcn_mfma_f32_16x16x32_bf16(af1, bg0, acc10, 0, 0, 0);
    acc11 = __builtin_amdgcn_mfma_f32_16x16x32_bf16(af1, bg1, acc11, 0, 0, 0);
    __syncthreads();
  }

  const int rbase = (lane >> 4) * 4;
  const int cbase = lane & 15;
  f32x4 accs[2][2] = {{acc00, acc01}, {acc10, acc11}};
#pragma unroll
  for (int i = 0; i < 2; ++i)
#pragma unroll
    for (int j = 0; j < 2; ++j) {
      const int n = n0 + wn + j * 16 + cbase;
      const float bv = bias[n];
#pragma unroll
      for (int r = 0; r < 4; ++r) {
        const int m = m0 + wm + i * 16 + rbase + r;
        const float v = accs[i][j][r] + bv;
        if (MODE == 0) {
          const int seg = n >> 10;         // 0:q 1:k 2:v
          const int c = n & 1023;
          const int e = c & 63;
          const int bhh = ((m >> 9) * H_) + (c >> 6);
          const int t = m & 511;
          if (seg == 0)
            qh[((size_t)bhh * T_ + t) * E_ + e] = f2bf(v * 0.125f);
          else if (seg == 1)
            Km[((size_t)bhh * S_ + L_ + t) * E_ + e] = f2bf(v);
          else
            Vtm[((size_t)bhh * E_ + e) * S_ + L_ + t] = f2bf(v);
        } else {
          outf[(size_t)m * N + n] = v;
        }
      }
    }
}

// -------- MFMA flash attention v2: block = (b,h, 128-q tile), 4 waves x 32 q -
__global__ __launch_bounds__(256) void attn_v2(const u16* __restrict__ qh,
                                               const u16* __restrict__ Km,
                                               const u16* __restrict__ Vtm,
                                               u16* __restrict__ y2) {
  __shared__ __align__(16) u16 Ks[64 * 72];
  __shared__ __align__(16) u16 Vts[64 * 72];
  __shared__ __align__(16) u16 Ps[4][32 * 72];

  const int tid = threadIdx.x;
  const int lane = tid & 63;
  const int w = tid >> 6;
  const int bh = blockIdx.x & 127;   // same-bh blocks 128 apart -> same XCD
  const int qt = blockIdx.x >> 7;
  const int h = bh & (H_ - 1);
  const int b = bh >> 4;
  const int t0 = qt * 128;

  const int col = lane & 15;
  const int fk = (lane >> 4) * 8;
  const int rbase = (lane >> 4) * 4;

  // Q fragments (A-layout), q pre-scaled by 1/sqrt(E) at GEMM epilogue
  const u16* qbase = qh + ((size_t)bh * T_ + t0 + w * 32) * E_;
  bf16x8 qf[2][2];
#pragma unroll
  for (int q2 = 0; q2 < 2; ++q2)
#pragma unroll
    for (int ks = 0; ks < 2; ++ks)
      qf[q2][ks] = *(const bf16x8*)(qbase + (q2 * 16 + col) * E_ + ks * 32 + fk);

  // staging role
  const int srow = tid >> 2;
  const int sc8 = (tid & 3) * 16;

  f32x4 Y[2][4];
  float m_run[2][4], l_run[2][4];
#pragma unroll
  for (int q2 = 0; q2 < 2; ++q2)
#pragma unroll
    for (int r = 0; r < 4; ++r) {
      Y[q2][r] = f32x4{0.f, 0.f, 0.f, 0.f};
      m_run[q2][r] = -1e30f;
      l_run[q2][r] = 0.f;
    }

  const int qmin_w = L_ + t0 + w * 32;
  const int nchunk = (L_ + t0 + 128) >> 6;
  const u16* KgB = Km + (size_t)bh * S_ * E_;
  const u16* VgB = Vtm + (size_t)bh * E_ * S_;

  for (int c0 = 0; c0 < nchunk; ++c0) {
    const int sbase = c0 << 6;
    __syncthreads();
    {
      const u16* kg = KgB + (size_t)(sbase + srow) * E_ + sc8;
      *(uint4*)(Ks + srow * 72 + sc8) = *(const uint4*)kg;
      *(uint4*)(Ks + srow * 72 + sc8 + 8) = *(const uint4*)(kg + 8);
      const u16* vg = VgB + (size_t)srow * S_ + sbase + sc8;
      *(uint4*)(Vts + srow * 72 + sc8) = *(const uint4*)vg;
      *(uint4*)(Vts + srow * 72 + sc8 + 8) = *(const uint4*)(vg + 8);
    }
    __syncthreads();

    if (sbase > qmin_w + 31) continue;  // beyond this wave's causal bound

    // ---- S = Q.K^T (D: row = q2*16 + rbase+r, col = key = kt*16 + col)
    f32x4 s[2][4];
#pragma unroll
    for (int kt = 0; kt < 4; ++kt) {
      const bf16x8 kb0 = *(const bf16x8*)(Ks + (kt * 16 + col) * 72 + fk);
      const bf16x8 kb1 = *(const bf16x8*)(Ks + (kt * 16 + col) * 72 + 32 + fk);
#pragma unroll
      for (int q2 = 0; q2 < 2; ++q2) {
        f32x4 z = {0.f, 0.f, 0.f, 0.f};
        z = __builtin_amdgcn_mfma_f32_16x16x32_bf16(qf[q2][0], kb0, z, 0, 0, 0);
        z = __builtin_amdgcn_mfma_f32_16x16x32_bf16(qf[q2][1], kb1, z, 0, 0, 0);
        s[q2][kt] = z;
      }
    }

    // ---- causal mask (straddling chunks only)
    if (sbase + 63 > qmin_w) {
#pragma unroll
      for (int q2 = 0; q2 < 2; ++q2) {
        const int bound = qmin_w + q2 * 16 + rbase;
#pragma unroll
        for (int kt = 0; kt < 4; ++kt) {
          const int keypos = sbase + kt * 16 + col;
#pragma unroll
          for (int r = 0; r < 4; ++r)
            if (keypos > bound + r) s[q2][kt][r] = -1e30f;
        }
      }
    }

    // ---- online softmax
    float alpha[2][4];
#pragma unroll
    for (int q2 = 0; q2 < 2; ++q2)
#pragma unroll
      for (int r = 0; r < 4; ++r) {
        float mp = fmaxf(fmaxf(s[q2][0][r], s[q2][1][r]),
                         fmaxf(s[q2][2][r], s[q2][3][r]));
        mp = fmaxf(mp, __shfl_xor(mp, 1, 64));
        mp = fmaxf(mp, __shfl_xor(mp, 2, 64));
        mp = fmaxf(mp, __shfl_xor(mp, 4, 64));
        mp = fmaxf(mp, __shfl_xor(mp, 8, 64));
        const float m_new = fmaxf(m_run[q2][r], mp);
        alpha[q2][r] = __expf(m_run[q2][r] - m_new);
        m_run[q2][r] = m_new;
        float ps = 0.f;
#pragma unroll
        for (int kt = 0; kt < 4; ++kt) {
          s[q2][kt][r] = __expf(s[q2][kt][r] - m_new);
          ps += s[q2][kt][r];
        }
        ps += __shfl_xor(ps, 1, 64);
        ps += __shfl_xor(ps, 2, 64);
        ps += __shfl_xor(ps, 4, 64);
        ps += __shfl_xor(ps, 8, 64);
        l_run[q2][r] = l_run[q2][r] * alpha[q2][r] + ps;
      }

    // ---- P -> wave-private LDS (C-layout -> A-layout)
    u16* psw = Ps[w];
#pragma unroll
    for (int q2 = 0; q2 < 2; ++q2)
#pragma unroll
      for (int kt = 0; kt < 4; ++kt)
#pragma unroll
        for (int r = 0; r < 4; ++r)
          psw[(q2 * 16 + rbase + r) * 72 + kt * 16 + col] = f2bf(s[q2][kt][r]);

    // ---- rescale Y, then Y += P.V
#pragma unroll
    for (int q2 = 0; q2 < 2; ++q2)
#pragma unroll
      for (int et = 0; et < 4; ++et)
#pragma unroll
        for (int r = 0; r < 4; ++r) Y[q2][et][r] *= alpha[q2][r];

    bf16x8 pa[2][2];
#pragma unroll
    for (int q2 = 0; q2 < 2; ++q2)
#pragma unroll
      for (int ks = 0; ks < 2; ++ks)
        pa[q2][ks] = *(const bf16x8*)(psw + (q2 * 16 + col) * 72 + ks * 32 + fk);

#pragma unroll
    for (int et = 0; et < 4; ++et) {
      const bf16x8 vb0 = *(const bf16x8*)(Vts + (et * 16 + col) * 72 + fk);
      const bf16x8 vb1 = *(const bf16x8*)(Vts + (et * 16 + col) * 72 + 32 + fk);
#pragma unroll
      for (int q2 = 0; q2 < 2; ++q2) {
        Y[q2][et] = __builtin_amdgcn_mfma_f32_16x16x32_bf16(pa[q2][0], vb0, Y[q2][et], 0, 0, 0);
        Y[q2][et] = __builtin_amdgcn_mfma_f32_16x16x32_bf16(pa[q2][1], vb1, Y[q2][et], 0, 0, 0);
      }
    }
  }

  // ---- epilogue
#pragma unroll
  for (int q2 = 0; q2 < 2; ++q2)
#pragma unroll
    for (int r = 0; r < 4; ++r) {
      const float rcp = 1.f / l_run[q2][r];
      const int t_out = t0 + w * 32 + q2 * 16 + rbase + r;
#pragma unroll
      for (int et = 0; et < 4; ++et)
        y2[((size_t)b * T_ + t_out) * C_ + h * E_ + et * 16 + col] =
            f2bf(Y[q2][et][r] * rcp);
    }
}

// ---------------- launch -----------------------------------------------------
extern "C" void kernel_launch(void* const* d_in, const int* in_sizes, int n_in,
                              void* d_out, int out_size, void* d_ws, size_t ws_size,
                              hipStream_t stream) {
  const float* x = (const float*)d_in[0];
  const float* kc = (const float*)d_in[1];
  const float* vc = (const float*)d_in[2];
  const float* Wqkv = (const float*)d_in[3];
  const float* bqkv = (const float*)d_in[4];
  const float* Wproj = (const float*)d_in[5];
  const float* bproj = (const float*)d_in[6];
  float* out = (float*)d_out;

  u16* qh = (u16*)d_ws;                  // 4194304
  u16* y2 = qh + 4194304;                // 4194304
  u16* xb = y2 + 4194304;                // 4194304
  u16* WqT = xb + 4194304;               // 3145728
  u16* WpT = WqT + 3145728;              // 1048576
  u16* Km = WpT + 1048576;               // 8*16*2560*64 = 20971520
  u16* Vtm = Km + 20971520;              // 20971520

  convert_f32_bf16<<<dim3(2048), 256, 0, stream>>>(x, xb);
  transpose_f32_bf16<<<dim3(48, 16), 256, 0, stream>>>(Wqkv, WqT, 1024, 3072);
  transpose_f32_bf16<<<dim3(16, 16), 256, 0, stream>>>(Wproj, WpT, 1024, 1024);
  prep_kv<<<dim3(128 * 32), 256, 0, stream>>>(kc, vc, Km, Vtm);

  // qkv = x @ Wqkv + bqkv -> qh (x0.125), Km[:, L:], Vtm[:, :, L:]
  gemm_bt<0><<<dim3(48, 64), 256, 0, stream>>>(xb, WqT, bqkv, qh, Km, Vtm, nullptr,
                                               4096, 3072, 1024);

  attn_v2<<<dim3(512), 256, 0, stream>>>(qh, Km, Vtm, y2);

  // out = y @ Wproj + bproj (f32 out)
  gemm_bt<1><<<dim3(16, 64), 256, 0, stream>>>(y2, WpT, bproj, nullptr, nullptr,
                                               nullptr, out, 4096, 1024, 1024);
}

// Round 5
// 353.788 us; speedup vs baseline: 14.6601x; 1.1888x over previous
//
#include <hip/hip_runtime.h>
#include <hip/hip_bf16.h>

typedef unsigned short u16;
typedef unsigned int u32;

constexpr int B_ = 8, T_ = 512, C_ = 1024, H_ = 16, E_ = 64, L_ = 2048;
constexpr int S_ = L_ + T_;  // 2560 merged KV length

typedef __bf16 bf16x8 __attribute__((ext_vector_type(8)));
typedef float f32x4 __attribute__((ext_vector_type(4)));

// 0.125 * log2(e): folds 1/sqrt(E) and the exp->exp2 base change into q
#define QSCALE 0.18033688011112042f

__device__ inline u16 f2bf(float f) {
  u32 u = __float_as_uint(f);
  u32 r = (u + 0x7fffu + ((u >> 16) & 1u)) >> 16;
  return (u16)r;
}

// packed f32x2 -> bf16x2 (RNE), hw v_cvt_pk where available
__device__ inline u32 pk2(float a, float b) {
  union { __hip_bfloat162 h; u32 u; } cv;
  cv.h = __float22bfloat162_rn(float2{a, b});
  return cv.u;
}

// async global->LDS, 16B per lane; lds base must be wave-uniform
__device__ inline void gload_lds16(const u16* g, u16* l) {
  __builtin_amdgcn_global_load_lds(
      (const __attribute__((address_space(1))) u32*)g,
      (__attribute__((address_space(3))) u32*)l, 16, 0, 0);
}

// ---------------- x (f32) -> bf16, 8 elements/thread -------------------------
__global__ __launch_bounds__(256) void convert_f32_bf16(const float* __restrict__ in,
                                                        u16* __restrict__ out) {
  const int i = blockIdx.x * 256 + threadIdx.x;
  const float4 a0 = ((const float4*)in)[i * 2];
  const float4 a1 = ((const float4*)in)[i * 2 + 1];
  uint4 p;
  p.x = pk2(a0.x, a0.y);
  p.y = pk2(a0.z, a0.w);
  p.z = pk2(a1.x, a1.y);
  p.w = pk2(a1.z, a1.w);
  ((uint4*)out)[i] = p;
}

// ------- transpose + downcast: in f32 (R x Ccols) -> out bf16 (Ccols x R) ----
__global__ __launch_bounds__(256) void transpose_f32_bf16(const float* __restrict__ in,
                                                          u16* __restrict__ out,
                                                          int R, int Ccols) {
  __shared__ u16 tile[64][65];
  const int r0 = blockIdx.y * 64;
  const int c0 = blockIdx.x * 64;
  const int tr = threadIdx.x >> 6;  // 0..3
  const int tc = threadIdx.x & 63;
#pragma unroll
  for (int i = 0; i < 16; ++i)
    tile[tr + i * 4][tc] = f2bf(in[(size_t)(r0 + tr + i * 4) * Ccols + c0 + tc]);
  __syncthreads();
#pragma unroll
  for (int i = 0; i < 16; ++i)
    out[(size_t)(c0 + tr + i * 4) * R + r0 + tc] = tile[tc][tr + i * 4];
}

// ---- prep: f32 KV cache -> merged bf16 Km[b,h,s,e] and Vtm[b,h,e,s] (s<L) ---
__global__ __launch_bounds__(256) void prep_kv(const float* __restrict__ kc,
                                               const float* __restrict__ vc,
                                               u16* __restrict__ Km,
                                               u16* __restrict__ Vtm) {
  __shared__ u16 vt[64 * 72];
  const int s0 = (blockIdx.x & 31) * 64;
  const int bh = blockIdx.x >> 5;
  const int tid = threadIdx.x;
  const int srow = tid >> 2;
  const int eq = (tid & 3) * 16;

  {
    const float* kp = kc + ((size_t)bh * L_ + s0 + srow) * E_ + eq;
    float kv[16];
    *(float4*)(kv + 0) = *(const float4*)(kp + 0);
    *(float4*)(kv + 4) = *(const float4*)(kp + 4);
    *(float4*)(kv + 8) = *(const float4*)(kp + 8);
    *(float4*)(kv + 12) = *(const float4*)(kp + 12);
    uint4 p0, p1;
    p0.x = pk2(kv[0], kv[1]);
    p0.y = pk2(kv[2], kv[3]);
    p0.z = pk2(kv[4], kv[5]);
    p0.w = pk2(kv[6], kv[7]);
    p1.x = pk2(kv[8], kv[9]);
    p1.y = pk2(kv[10], kv[11]);
    p1.z = pk2(kv[12], kv[13]);
    p1.w = pk2(kv[14], kv[15]);
    u16* kd = Km + ((size_t)bh * S_ + s0 + srow) * E_ + eq;
    *(uint4*)kd = p0;
    *(uint4*)(kd + 8) = p1;
  }
  {
    const float* vp = vc + ((size_t)bh * L_ + s0 + srow) * E_ + eq;
    float vv[16];
    *(float4*)(vv + 0) = *(const float4*)(vp + 0);
    *(float4*)(vv + 4) = *(const float4*)(vp + 4);
    *(float4*)(vv + 8) = *(const float4*)(vp + 8);
    *(float4*)(vv + 12) = *(const float4*)(vp + 12);
    uint4 p0, p1;
    p0.x = pk2(vv[0], vv[1]);
    p0.y = pk2(vv[2], vv[3]);
    p0.z = pk2(vv[4], vv[5]);
    p0.w = pk2(vv[6], vv[7]);
    p1.x = pk2(vv[8], vv[9]);
    p1.y = pk2(vv[10], vv[11]);
    p1.z = pk2(vv[12], vv[13]);
    p1.w = pk2(vv[14], vv[15]);
    *(uint4*)(vt + srow * 72 + eq) = p0;
    *(uint4*)(vt + srow * 72 + eq + 8) = p1;
  }
  __syncthreads();
  {
    const int erow = tid >> 2;
    const int sq = (tid & 3) * 16;
    u16 o[16];
#pragma unroll
    for (int j = 0; j < 16; ++j) o[j] = vt[(sq + j) * 72 + erow];
    u16* vd = Vtm + ((size_t)bh * E_ + erow) * S_ + s0 + sq;
    *(uint4*)vd = *(uint4*)(o + 0);
    *(uint4*)(vd + 8) = *(uint4*)(o + 8);
  }
}

// --------- m97-style GEMM: C[M,N] = A[M,K] @ BT[N,K]^T + bias[n] -------------
// 128x128 tile, BK=32, global_load_lds staging, 4 waves each 64x64.
// MODE 0: scatter qkv: q (xQSCALE) -> qh[b,h,t,e]; k -> Km[..,L+t,e]; v -> Vtm[..,e,L+t]
// MODE 1: f32 row-major store to outf
template <int MODE>
__global__ __launch_bounds__(256) void gemm128(const u16* __restrict__ A,
                                               const u16* __restrict__ BT,
                                               const float* __restrict__ bias,
                                               u16* __restrict__ qh,
                                               u16* __restrict__ Km,
                                               u16* __restrict__ Vtm,
                                               float* __restrict__ outf,
                                               int M, int N, int K) {
  __shared__ __align__(16) u16 As[128 * 32];
  __shared__ __align__(16) u16 Bs[128 * 32];
  const int tid = threadIdx.x;
  const int lane = tid & 63;
  const int w = tid >> 6;
  const int m0 = blockIdx.y * 128;
  const int n0 = blockIdx.x * 128;
  const int wm = (w >> 1) * 64;
  const int wn = (w & 1) * 64;
  const int fm = lane & 15;
  const int fk = (lane >> 4) * 8;

  // staging: wave w covers rows [w*16, w*16+16) and +64; lane l -> row l>>2, col (l&3)*8
  const int srow = w * 16 + (lane >> 2);
  const int scol = (lane & 3) * 8;
  const u16* Ag = A + (size_t)(m0 + srow) * K + scol;
  const u16* Bg = BT + (size_t)(n0 + srow) * K + scol;
  u16* AsU = As + w * 512;  // wave-uniform LDS bases (u16 units)
  u16* BsU = Bs + w * 512;

  f32x4 acc[4][4];
#pragma unroll
  for (int i = 0; i < 4; ++i)
#pragma unroll
    for (int j = 0; j < 4; ++j) acc[i][j] = f32x4{0.f, 0.f, 0.f, 0.f};

  for (int k0 = 0; k0 < K; k0 += 32) {
    gload_lds16(Ag, AsU);
    gload_lds16(Ag + (size_t)64 * K, AsU + 2048);
    gload_lds16(Bg, BsU);
    gload_lds16(Bg + (size_t)64 * K, BsU + 2048);
    Ag += 32;
    Bg += 32;
    __syncthreads();
    bf16x8 af[4], bf[4];
#pragma unroll
    for (int i = 0; i < 4; ++i)
      af[i] = *(const bf16x8*)(As + (wm + i * 16 + fm) * 32 + fk);
#pragma unroll
    for (int j = 0; j < 4; ++j)
      bf[j] = *(const bf16x8*)(Bs + (wn + j * 16 + fm) * 32 + fk);
#pragma unroll
    for (int i = 0; i < 4; ++i)
#pragma unroll
      for (int j = 0; j < 4; ++j)
        acc[i][j] = __builtin_amdgcn_mfma_f32_16x16x32_bf16(af[i], bf[j], acc[i][j], 0, 0, 0);
    __syncthreads();
  }

  const int rbase = (lane >> 4) * 4;
  const int cbase = lane & 15;
#pragma unroll
  for (int i = 0; i < 4; ++i)
#pragma unroll
    for (int j = 0; j < 4; ++j) {
      const int n = n0 + wn + j * 16 + cbase;
      const float bv = bias[n];
#pragma unroll
      for (int r = 0; r < 4; ++r) {
        const int m = m0 + wm + i * 16 + rbase + r;
        const float v = acc[i][j][r] + bv;
        if (MODE == 0) {
          const int seg = n >> 10;  // 0:q 1:k 2:v
          const int c = n & 1023;
          const int e = c & 63;
          const int bhh = ((m >> 9) * H_) + (c >> 6);
          const int t = m & 511;
          if (seg == 0)
            qh[((size_t)bhh * T_ + t) * E_ + e] = f2bf(v * QSCALE);
          else if (seg == 1)
            Km[((size_t)bhh * S_ + L_ + t) * E_ + e] = f2bf(v);
          else
            Vtm[((size_t)bhh * E_ + e) * S_ + L_ + t] = f2bf(v);
        } else {
          outf[(size_t)m * N + n] = v;
        }
      }
    }
}

// ----- MFMA flash attention v3: no-max exp2 softmax, l via ones-MFMA ---------
// block = (b,h, 128-q tile), 4 waves x 32 q. Scores pre-scaled via QSCALE in q.
__global__ __launch_bounds__(256) void attn_v3(const u16* __restrict__ qh,
                                               const u16* __restrict__ Km,
                                               const u16* __restrict__ Vtm,
                                               u16* __restrict__ y2) {
  __shared__ __align__(16) u16 Ks[64 * 72];
  __shared__ __align__(16) u16 Vts[64 * 72];
  __shared__ __align__(16) u16 Ps[4][32 * 72];

  const int tid = threadIdx.x;
  const int lane = tid & 63;
  const int w = tid >> 6;
  const int bh = blockIdx.x & 127;  // same-bh blocks 128 apart
  const int qt = blockIdx.x >> 7;
  const int h = bh & (H_ - 1);
  const int b = bh >> 4;
  const int t0 = qt * 128;

  const int col = lane & 15;
  const int fk = (lane >> 4) * 8;
  const int rbase = (lane >> 4) * 4;

  const u16* qbase = qh + ((size_t)bh * T_ + t0 + w * 32) * E_;
  bf16x8 qf[2][2];
#pragma unroll
  for (int q2 = 0; q2 < 2; ++q2)
#pragma unroll
    for (int ks = 0; ks < 2; ++ks)
      qf[q2][ks] = *(const bf16x8*)(qbase + (q2 * 16 + col) * E_ + ks * 32 + fk);

  const int srow = tid >> 2;
  const int sc8 = (tid & 3) * 16;

  f32x4 Yt[2][4];   // Y^T: row=e_local, col=q_local
  f32x4 lf[2];      // softmax denominators, col=q_local (rows replicated)
#pragma unroll
  for (int q2 = 0; q2 < 2; ++q2) {
    lf[q2] = f32x4{0.f, 0.f, 0.f, 0.f};
#pragma unroll
    for (int et = 0; et < 4; ++et) Yt[q2][et] = f32x4{0.f, 0.f, 0.f, 0.f};
  }

  const bf16x8 ones = {(__bf16)1.f, (__bf16)1.f, (__bf16)1.f, (__bf16)1.f,
                       (__bf16)1.f, (__bf16)1.f, (__bf16)1.f, (__bf16)1.f};

  const int qmin_w = L_ + t0 + w * 32;
  const int nchunk = (L_ + t0 + 128) >> 6;
  const u16* KgB = Km + (size_t)bh * S_ * E_;
  const u16* VgB = Vtm + (size_t)bh * E_ * S_;

  for (int c0 = 0; c0 < nchunk; ++c0) {
    const int sbase = c0 << 6;
    __syncthreads();
    {
      const u16* kg = KgB + (size_t)(sbase + srow) * E_ + sc8;
      *(uint4*)(Ks + srow * 72 + sc8) = *(const uint4*)kg;
      *(uint4*)(Ks + srow * 72 + sc8 + 8) = *(const uint4*)(kg + 8);
      const u16* vg = VgB + (size_t)srow * S_ + sbase + sc8;
      *(uint4*)(Vts + srow * 72 + sc8) = *(const uint4*)vg;
      *(uint4*)(Vts + srow * 72 + sc8 + 8) = *(const uint4*)(vg + 8);
    }
    __syncthreads();

    if (sbase > qmin_w + 31) continue;  // fully beyond this wave's causal bound

    // ---- S = Q.K^T (D: row=q_local, col=key_local)
    f32x4 s[2][4];
#pragma unroll
    for (int kt = 0; kt < 4; ++kt) {
      const bf16x8 kb0 = *(const bf16x8*)(Ks + (kt * 16 + col) * 72 + fk);
      const bf16x8 kb1 = *(const bf16x8*)(Ks + (kt * 16 + col) * 72 + 32 + fk);
#pragma unroll
      for (int q2 = 0; q2 < 2; ++q2) {
        f32x4 z = {0.f, 0.f, 0.f, 0.f};
        z = __builtin_amdgcn_mfma_f32_16x16x32_bf16(qf[q2][0], kb0, z, 0, 0, 0);
        z = __builtin_amdgcn_mfma_f32_16x16x32_bf16(qf[q2][1], kb1, z, 0, 0, 0);
        s[q2][kt] = z;
      }
    }

    // ---- causal mask (straddling chunks only)
    if (sbase + 63 > qmin_w) {
#pragma unroll
      for (int q2 = 0; q2 < 2; ++q2) {
        const int bound = qmin_w + q2 * 16 + rbase;
#pragma unroll
        for (int kt = 0; kt < 4; ++kt) {
          const int keypos = sbase + kt * 16 + col;
#pragma unroll
          for (int r = 0; r < 4; ++r)
            if (keypos > bound + r) s[q2][kt][r] = -1e30f;
        }
      }
    }

    // ---- p = exp2(s)  (no max tracking: scores bounded, f32 can't overflow)
#pragma unroll
    for (int q2 = 0; q2 < 2; ++q2)
#pragma unroll
      for (int kt = 0; kt < 4; ++kt)
#pragma unroll
        for (int r = 0; r < 4; ++r) s[q2][kt][r] = exp2f(s[q2][kt][r]);

    // ---- P -> wave-private LDS (C-layout -> A/B-layout), packed cvt
    u16* psw = Ps[w];
#pragma unroll
    for (int q2 = 0; q2 < 2; ++q2)
#pragma unroll
      for (int kt = 0; kt < 4; ++kt) {
        const u32 p01 = pk2(s[q2][kt][0], s[q2][kt][1]);
        const u32 p23 = pk2(s[q2][kt][2], s[q2][kt][3]);
        const int a = (q2 * 16 + rbase) * 72 + kt * 16 + col;
        psw[a] = (u16)p01;
        psw[a + 72] = (u16)(p01 >> 16);
        psw[a + 144] = (u16)p23;
        psw[a + 216] = (u16)(p23 >> 16);
      }

    bf16x8 pa[2][2];
#pragma unroll
    for (int q2 = 0; q2 < 2; ++q2)
#pragma unroll
      for (int ks = 0; ks < 2; ++ks)
        pa[q2][ks] = *(const bf16x8*)(psw + (q2 * 16 + col) * 72 + ks * 32 + fk);

    // ---- l += P @ 1 (ones-MFMA; D col=q, all rows equal)
#pragma unroll
    for (int q2 = 0; q2 < 2; ++q2) {
      lf[q2] = __builtin_amdgcn_mfma_f32_16x16x32_bf16(ones, pa[q2][0], lf[q2], 0, 0, 0);
      lf[q2] = __builtin_amdgcn_mfma_f32_16x16x32_bf16(ones, pa[q2][1], lf[q2], 0, 0, 0);
    }

    // ---- Y^T += V^T.P^T  (A=V^T frag, B=P frag; D: row=e_local, col=q_local)
#pragma unroll
    for (int et = 0; et < 4; ++et) {
      const bf16x8 vb0 = *(const bf16x8*)(Vts + (et * 16 + col) * 72 + fk);
      const bf16x8 vb1 = *(const bf16x8*)(Vts + (et * 16 + col) * 72 + 32 + fk);
#pragma unroll
      for (int q2 = 0; q2 < 2; ++q2) {
        Yt[q2][et] = __builtin_amdgcn_mfma_f32_16x16x32_bf16(vb0, pa[q2][0], Yt[q2][et], 0, 0, 0);
        Yt[q2][et] = __builtin_amdgcn_mfma_f32_16x16x32_bf16(vb1, pa[q2][1], Yt[q2][et], 0, 0, 0);
      }
    }
  }

  // ---- epilogue: lane holds q = col; e = et*16 + rbase + r -> 8B stores
#pragma unroll
  for (int q2 = 0; q2 < 2; ++q2) {
    const float rl = 1.f / lf[q2][0];
    const int t_out = t0 + w * 32 + q2 * 16 + col;
    u16* yp = y2 + ((size_t)b * T_ + t_out) * C_ + h * E_ + rbase;
#pragma unroll
    for (int et = 0; et < 4; ++et) {
      uint2 v;
      v.x = pk2(Yt[q2][et][0] * rl, Yt[q2][et][1] * rl);
      v.y = pk2(Yt[q2][et][2] * rl, Yt[q2][et][3] * rl);
      *(uint2*)(yp + et * 16) = v;
    }
  }
}

// ---------------- launch -----------------------------------------------------
extern "C" void kernel_launch(void* const* d_in, const int* in_sizes, int n_in,
                              void* d_out, int out_size, void* d_ws, size_t ws_size,
                              hipStream_t stream) {
  const float* x = (const float*)d_in[0];
  const float* kc = (const float*)d_in[1];
  const float* vc = (const float*)d_in[2];
  const float* Wqkv = (const float*)d_in[3];
  const float* bqkv = (const float*)d_in[4];
  const float* Wproj = (const float*)d_in[5];
  const float* bproj = (const float*)d_in[6];
  float* out = (float*)d_out;

  u16* qh = (u16*)d_ws;                  // 4194304
  u16* y2 = qh + 4194304;                // 4194304
  u16* xb = y2 + 4194304;                // 4194304
  u16* WqT = xb + 4194304;               // 3145728
  u16* WpT = WqT + 3145728;              // 1048576
  u16* Km = WpT + 1048576;               // 20971520
  u16* Vtm = Km + 20971520;              // 20971520

  convert_f32_bf16<<<dim3(2048), 256, 0, stream>>>(x, xb);
  transpose_f32_bf16<<<dim3(48, 16), 256, 0, stream>>>(Wqkv, WqT, 1024, 3072);
  transpose_f32_bf16<<<dim3(16, 16), 256, 0, stream>>>(Wproj, WpT, 1024, 1024);
  prep_kv<<<dim3(128 * 32), 256, 0, stream>>>(kc, vc, Km, Vtm);

  // qkv = x @ Wqkv + bqkv -> qh (xQSCALE), Km[:, L:], Vtm[:, :, L:]
  gemm128<0><<<dim3(24, 32), 256, 0, stream>>>(xb, WqT, bqkv, qh, Km, Vtm, nullptr,
                                               4096, 3072, 1024);

  attn_v3<<<dim3(512), 256, 0, stream>>>(qh, Km, Vtm, y2);

  // out = y @ Wproj + bproj (f32 out)
  gemm128<1><<<dim3(8, 32), 256, 0, stream>>>(y2, WpT, bproj, nullptr, nullptr,
                                              nullptr, out, 4096, 1024, 1024);
}